// Round 1
// baseline (439.500 us; speedup 1.0000x reference)
//
#include <hip/hip_runtime.h>

#define N_NODES 50000
#define N_GRAPHS 128
#define HID 512

// ---------------------------------------------------------------------------
// counts[g] = number of paths whose anchor node walk2[0][i] belongs to graph g
// ---------------------------------------------------------------------------
__global__ void count_paths_kernel(const int* __restrict__ w2,
                                   const int* __restrict__ batch,
                                   int* __restrict__ counts) {
    int i = blockIdx.x * blockDim.x + threadIdx.x;
    if (i < N_NODES) {
        int g = batch[w2[i]];
        atomicAdd(&counts[g], 1);
    }
}

// ---------------------------------------------------------------------------
// Psum[g][c] = sum over paths i in graph g of sum over the 12 walk entries of
//              x[node][c].   (Gather-reduce on the INPUT x only — the layers
//              are affine, so the GEMM is pulled outside the pooling.)
//
// grid = (128 path-chunks, 4 col-chunks), block = 512 (8 waves).
// Each block privatizes a [128 graphs][128 cols] fp32 accumulator in LDS
// (exactly 64 KB -> 2 blocks/CU). A wave processes one path at a time:
// lane L covers cols colbase+2L, colbase+2L+1 via one float2 load per entry,
// sums the 12 entries in registers, then does 2 LDS atomic adds.
// LDS layout is permuted: .x parts at [g][lane], .y parts at [g][64+lane]
// -> ds_add addresses are lane-consecutive -> 2 lanes/bank (free on gfx950).
// ---------------------------------------------------------------------------
__global__ __launch_bounds__(512)
void pool_accum_kernel(const float* __restrict__ x,
                       const int* __restrict__ w2,
                       const int* __restrict__ w3,
                       const int* __restrict__ w4,
                       const int* __restrict__ batch,
                       float* __restrict__ Psum) {
    __shared__ float lds[N_GRAPHS * 128];
    const int colbase = blockIdx.y * 128;
    const int lane = threadIdx.x & 63;
    const int wave = threadIdx.x >> 6;

    for (int idx = threadIdx.x; idx < N_GRAPHS * 128; idx += 512)
        lds[idx] = 0.f;
    __syncthreads();

    const int nchunks = gridDim.x;
    const int pc = (N_NODES + nchunks - 1) / nchunks;
    const int start = blockIdx.x * pc;
    const int end = min(N_NODES, start + pc);

    for (int i = start + wave; i < end; i += 8) {
        int n[12];
        n[0]  = w2[i];
        n[1]  = w2[N_NODES + i];
        n[2]  = w2[2 * N_NODES + i];
        n[3]  = w3[i];
        n[4]  = w3[N_NODES + i];
        n[5]  = w3[2 * N_NODES + i];
        n[6]  = w3[3 * N_NODES + i];
        n[7]  = w4[i];
        n[8]  = w4[N_NODES + i];
        n[9]  = w4[2 * N_NODES + i];
        n[10] = w4[3 * N_NODES + i];
        n[11] = w4[4 * N_NODES + i];
        const int g = batch[n[0]];

        float sx = 0.f, sy = 0.f;
#pragma unroll
        for (int j = 0; j < 12; ++j) {
            const float2 v =
                *(const float2*)&x[(size_t)n[j] * HID + colbase + 2 * lane];
            sx += v.x;
            sy += v.y;
        }
        atomicAdd(&lds[g * 128 + lane], sx);
        atomicAdd(&lds[g * 128 + 64 + lane], sy);
    }
    __syncthreads();

    // Flush LDS accumulator to global Psum (un-permute the column index).
    for (int idx = threadIdx.x; idx < N_GRAPHS * 128; idx += 512) {
        const float v = lds[idx];
        if (v != 0.f) {
            const int g = idx >> 7;
            const int j = idx & 127;
            const int col = colbase + 2 * (j & 63) + (j >> 6);
            atomicAdd(&Psum[g * HID + col], v);
        }
    }
}

// ---------------------------------------------------------------------------
// out[r][c] += sum_k A[r][k] * W[k][c]  (+ 12*mask(r)*bias[c] on k-chunk 0)
// A is optionally row-scaled by 1/max(counts[r],1) (layer 0: A = Psum).
// grid = (8 col-tiles x 8 row-tiles x 4 k-chunks), block = 256.
// Thread: col = ct*64 + (t&63); wave wv owns rows rt*16 + wv*4 .. +3 (4-way
// FMA ILP per W load; A tile staged in LDS, broadcast reads).
// Output row stride is 1536 (the concatenated [128 x 3*512] output).
// ---------------------------------------------------------------------------
__global__ __launch_bounds__(256)
void layer_gemm_kernel(const float* __restrict__ A, int lda, int scaleA,
                       const float* __restrict__ W,
                       const float* __restrict__ bias,
                       const int* __restrict__ counts,
                       float* __restrict__ out) {
    __shared__ float Alds[16][128];
    const int ct = blockIdx.x, rt = blockIdx.y, ks = blockIdx.z;
    const int t = threadIdx.x;
    const int c = ct * 64 + (t & 63);
    const int wv = t >> 6;
    const int k0 = ks * 128;

    for (int idx = t; idx < 16 * 32; idx += 256) {
        const int rr = idx >> 5;
        const int kk = (idx & 31) * 4;
        const int row = rt * 16 + rr;
        float4 v = *(const float4*)&A[(size_t)row * lda + k0 + kk];
        if (scaleA) {
            const float inv = 1.f / (float)max(counts[row], 1);
            v.x *= inv; v.y *= inv; v.z *= inv; v.w *= inv;
        }
        *(float4*)&Alds[rr][kk] = v;
    }
    __syncthreads();

    const int r0 = rt * 16 + wv * 4;
    float a0 = 0.f, a1 = 0.f, a2 = 0.f, a3 = 0.f;
#pragma unroll 8
    for (int k = 0; k < 128; ++k) {
        const float w = W[(size_t)(k0 + k) * HID + c];
        a0 += Alds[wv * 4 + 0][k] * w;
        a1 += Alds[wv * 4 + 1][k] * w;
        a2 += Alds[wv * 4 + 2][k] * w;
        a3 += Alds[wv * 4 + 3][k] * w;
    }
    if (ks == 0) {
        const float bc = bias[c];
        a0 += (counts[r0 + 0] > 0 ? 12.f : 0.f) * bc;
        a1 += (counts[r0 + 1] > 0 ? 12.f : 0.f) * bc;
        a2 += (counts[r0 + 2] > 0 ? 12.f : 0.f) * bc;
        a3 += (counts[r0 + 3] > 0 ? 12.f : 0.f) * bc;
    }
    atomicAdd(&out[(size_t)(r0 + 0) * 1536 + c], a0);
    atomicAdd(&out[(size_t)(r0 + 1) * 1536 + c], a1);
    atomicAdd(&out[(size_t)(r0 + 2) * 1536 + c], a2);
    atomicAdd(&out[(size_t)(r0 + 3) * 1536 + c], a3);
}

extern "C" void kernel_launch(void* const* d_in, const int* in_sizes, int n_in,
                              void* d_out, int out_size, void* d_ws, size_t ws_size,
                              hipStream_t stream) {
    const float* x     = (const float*)d_in[0];
    const int*   w2    = (const int*)d_in[1];
    const int*   w3    = (const int*)d_in[2];
    const int*   w4    = (const int*)d_in[3];
    const int*   batch = (const int*)d_in[4];
    const float* W0    = (const float*)d_in[5];
    const float* b0    = (const float*)d_in[6];
    const float* W1    = (const float*)d_in[7];
    const float* b1    = (const float*)d_in[8];
    const float* W2    = (const float*)d_in[9];
    const float* b2    = (const float*)d_in[10];
    float* out = (float*)d_out;

    float* Psum = (float*)d_ws;                                 // 128*512 f32
    int* counts = (int*)((char*)d_ws + N_GRAPHS * HID * 4);     // 128 i32

    hipMemsetAsync(d_ws, 0, N_GRAPHS * HID * 4 + N_GRAPHS * 4, stream);
    hipMemsetAsync(d_out, 0, (size_t)out_size * 4, stream);

    count_paths_kernel<<<(N_NODES + 255) / 256, 256, 0, stream>>>(w2, batch, counts);
    pool_accum_kernel<<<dim3(128, 4), 512, 0, stream>>>(x, w2, w3, w4, batch, Psum);

    layer_gemm_kernel<<<dim3(8, 8, 4), 256, 0, stream>>>(Psum, HID, 1, W0, b0, counts, out);
    layer_gemm_kernel<<<dim3(8, 8, 4), 256, 0, stream>>>(out, 1536, 0, W1, b1, counts, out + 512);
    layer_gemm_kernel<<<dim3(8, 8, 4), 256, 0, stream>>>(out + 512, 1536, 0, W2, b2, counts, out + 1024);
}

// Round 2
// 273.193 us; speedup vs baseline: 1.6088x; 1.6088x over previous
//
#include <hip/hip_runtime.h>

#define N_NODES 50000
#define N_GRAPHS 128
#define HID 512

// Split-K GEMM geometry: Psum[128 x 512] = C[128 x K] * x[K x 512]
#define KSPLIT 128
#define KSPAN  416                            // nodes per split = 13 chunks of 32
#define KPAD   (KSPLIT * KSPAN)               // 53248 padded K (zero tail)
#define C8_BYTES  ((size_t)N_GRAPHS * KPAD)   // 6,815,744
#define PSUM_OFF  C8_BYTES
#define COUNTS_OFF (PSUM_OFF + (size_t)N_GRAPHS * HID * 4)
#define ZERO_BYTES (COUNTS_OFF + 512)
#define PART_OFF  ZERO_BYTES
#define PART_BYTES ((size_t)KSPLIT * N_GRAPHS * HID * 4)   // 33.6 MB

typedef __attribute__((ext_vector_type(8))) short bf16x8;
typedef __attribute__((ext_vector_type(16))) float f32x16;

struct U4 { uint2 a, b; };

// ---------------------------------------------------------------------------
// Build byte-packed counts matrix C8[g][node] (row stride KPAD, zero-padded
// tail) + per-graph path counts (LDS histogram -> 128 atomics per block).
// ---------------------------------------------------------------------------
__global__ __launch_bounds__(256)
void build_c_kernel(const int* __restrict__ w2, const int* __restrict__ w3,
                    const int* __restrict__ w4, const int* __restrict__ batch,
                    unsigned int* __restrict__ C32, int* __restrict__ counts) {
    __shared__ int hist[N_GRAPHS];
    const int t = threadIdx.x;
    if (t < N_GRAPHS) hist[t] = 0;
    __syncthreads();
    const int i = blockIdx.x * 256 + t;
    if (i < N_NODES) {
        const int a = w2[i];            // walk2[0][i] — path anchor
        const int g = batch[a];
        atomicAdd(&hist[g], 1);
        unsigned int* row = C32 + (size_t)g * (KPAD / 4);
        int nn[12];
        nn[0]  = a;
        nn[1]  = w2[N_NODES + i];
        nn[2]  = w2[2 * N_NODES + i];
        nn[3]  = w3[i];
        nn[4]  = w3[N_NODES + i];
        nn[5]  = w3[2 * N_NODES + i];
        nn[6]  = w3[3 * N_NODES + i];
        nn[7]  = w4[i];
        nn[8]  = w4[N_NODES + i];
        nn[9]  = w4[2 * N_NODES + i];
        nn[10] = w4[3 * N_NODES + i];
        nn[11] = w4[4 * N_NODES + i];
#pragma unroll
        for (int j = 0; j < 12; ++j) {
            const int nd = nn[j];
            atomicAdd(&row[nd >> 2], 1u << ((nd & 3) * 8));
        }
    }
    __syncthreads();
    if (t < N_GRAPHS) { const int hv = hist[t]; if (hv) atomicAdd(&counts[t], hv); }
}

// u8 counts (exact in bf16) -> A fragment, k-ascending
__device__ inline bf16x8 cnt_frag(uint2 v) {
    bf16x8 r;
#pragma unroll
    for (int j = 0; j < 4; ++j) {
        r[j]     = (short)(__builtin_bit_cast(unsigned, (float)((v.x >> (8 * j)) & 0xFFu)) >> 16);
        r[4 + j] = (short)(__builtin_bit_cast(unsigned, (float)((v.y >> (8 * j)) & 0xFFu)) >> 16);
    }
    return r;
}

// ---------------------------------------------------------------------------
// Split-K MFMA GEMM. Block: M=128 (all graphs) x N=128 cols, K-span 416.
// grid=(4 col-tiles, 128 k-splits), 512 threads (8 waves).
// Wave w: n-subtile ns=w&3, m-tile pair mh=w>>2 -> two 32x32 acc tiles.
// x staged per 32-k chunk as TRANSPOSED hi/lo bf16 [c][k] (row stride 18
// u32 -> b64 LDS ops stay ~conflict-free); hi/lo split keeps fp32 accuracy.
// A (counts) loaded straight from global as uint2 per lane.
// Epilogue: plain stores to part[ks] (template ATOMIC=1 falls back to
// atomicAdd into Psum if the workspace is too small for part).
// ---------------------------------------------------------------------------
template <int ATOMIC>
__global__ __launch_bounds__(512, 4)
void pool_gemm_kernel(const float* __restrict__ x,
                      const unsigned char* __restrict__ C8,
                      float* __restrict__ dst) {
    __shared__ unsigned int BH[128 * 18];
    __shared__ unsigned int BL[128 * 18];

    const int nt = blockIdx.x;
    const int ks = blockIdx.y;
    const int t = threadIdx.x;
    const int lane = t & 63;
    const int w = t >> 6;
    const int ns = w & 3;
    const int mh = w >> 2;
    const int n = lane & 31;
    const int h = lane >> 5;

    const int colbase = nt * 128;
    const int c = t & 127;          // staging column
    const int strip = t >> 7;       // staging k-strip (0..3)

    const unsigned char* arow0 = C8 + (size_t)(mh * 64 + n) * KPAD;
    const unsigned char* arow1 = arow0 + (size_t)32 * KPAD;

    f32x16 acc0, acc1;
#pragma unroll
    for (int i = 0; i < 16; ++i) { acc0[i] = 0.f; acc1[i] = 0.f; }

    for (int ch = 0; ch < KSPAN / 32; ++ch) {
        const int k0 = ks * KSPAN + ch * 32;

        // A prefetch (2 m-tiles x 2 k-steps), 8 bytes per lane each
        const int aoff = k0 + h * 8;
        const uint2 a00 = *(const uint2*)(arow0 + aoff);
        const uint2 a01 = *(const uint2*)(arow0 + aoff + 16);
        const uint2 a10 = *(const uint2*)(arow1 + aoff);
        const uint2 a11 = *(const uint2*)(arow1 + aoff + 16);

        // Stage x rows k0..k0+31 for this block's 128 cols (coalesced 256B/instr)
        const int kb = k0 + strip * 8;
        float v[8];
#pragma unroll
        for (int j = 0; j < 8; ++j) {
            const int k = kb + j;
            v[j] = (k < N_NODES) ? x[(size_t)k * HID + colbase + c] : 0.f;
        }
        unsigned hw[4], lw[4];
#pragma unroll
        for (int j = 0; j < 4; ++j) {
            const unsigned u0 = __builtin_bit_cast(unsigned, v[2 * j]);
            const unsigned u1 = __builtin_bit_cast(unsigned, v[2 * j + 1]);
            const unsigned h0 = u0 & 0xFFFF0000u, h1 = u1 & 0xFFFF0000u;
            hw[j] = (h0 >> 16) | h1;
            const float r0 = v[2 * j] - __builtin_bit_cast(float, h0);
            const float r1 = v[2 * j + 1] - __builtin_bit_cast(float, h1);
            lw[j] = (__builtin_bit_cast(unsigned, r0) >> 16) |
                    (__builtin_bit_cast(unsigned, r1) & 0xFFFF0000u);
        }
        __syncthreads();   // previous chunk's frag reads complete
        const int widx = c * 18 + strip * 4;
        *(uint2*)&BH[widx]     = make_uint2(hw[0], hw[1]);
        *(uint2*)&BH[widx + 2] = make_uint2(hw[2], hw[3]);
        *(uint2*)&BL[widx]     = make_uint2(lw[0], lw[1]);
        *(uint2*)&BL[widx + 2] = make_uint2(lw[2], lw[3]);
        __syncthreads();

#pragma unroll
        for (int kk = 0; kk < 2; ++kk) {
            const int bidx = (ns * 32 + n) * 18 + kk * 8 + h * 4;
            U4 uh, ul;
            uh.a = *(const uint2*)&BH[bidx];
            uh.b = *(const uint2*)&BH[bidx + 2];
            ul.a = *(const uint2*)&BL[bidx];
            ul.b = *(const uint2*)&BL[bidx + 2];
            const bf16x8 bh = __builtin_bit_cast(bf16x8, uh);
            const bf16x8 bl = __builtin_bit_cast(bf16x8, ul);
            const bf16x8 af0 = cnt_frag(kk ? a01 : a00);
            const bf16x8 af1 = cnt_frag(kk ? a11 : a10);
            acc0 = __builtin_amdgcn_mfma_f32_32x32x16_bf16(af0, bh, acc0, 0, 0, 0);
            acc1 = __builtin_amdgcn_mfma_f32_32x32x16_bf16(af1, bh, acc1, 0, 0, 0);
            acc0 = __builtin_amdgcn_mfma_f32_32x32x16_bf16(af0, bl, acc0, 0, 0, 0);
            acc1 = __builtin_amdgcn_mfma_f32_32x32x16_bf16(af1, bl, acc1, 0, 0, 0);
        }
    }

    // Epilogue: C/D layout col=lane&31, row=(r&3)+8*(r>>2)+4*(lane>>5)
    const int col = colbase + ns * 32 + n;
    float* outp = ATOMIC ? dst : dst + (size_t)ks * N_GRAPHS * HID;
#pragma unroll
    for (int r = 0; r < 16; ++r) {
        const int row0 = mh * 64 + (r & 3) + 8 * (r >> 2) + 4 * h;
        if (ATOMIC) {
            atomicAdd(&outp[(size_t)row0 * HID + col], acc0[r]);
            atomicAdd(&outp[(size_t)(row0 + 32) * HID + col], acc1[r]);
        } else {
            outp[(size_t)row0 * HID + col] = acc0[r];
            outp[(size_t)(row0 + 32) * HID + col] = acc1[r];
        }
    }
}

// ---------------------------------------------------------------------------
// Psum[g][c] = sum over the 128 split-K partials (coalesced streams)
// ---------------------------------------------------------------------------
__global__ __launch_bounds__(256)
void reduce_part_kernel(const float* __restrict__ part, float* __restrict__ Psum) {
    const int id = blockIdx.x * 256 + threadIdx.x;
    float s0 = 0.f, s1 = 0.f, s2 = 0.f, s3 = 0.f;
    for (int s = 0; s < KSPLIT; s += 4) {
        s0 += part[(size_t)s * (N_GRAPHS * HID) + id];
        s1 += part[(size_t)(s + 1) * (N_GRAPHS * HID) + id];
        s2 += part[(size_t)(s + 2) * (N_GRAPHS * HID) + id];
        s3 += part[(size_t)(s + 3) * (N_GRAPHS * HID) + id];
    }
    Psum[id] = (s0 + s1) + (s2 + s3);
}

// ---------------------------------------------------------------------------
// out[r][c] += sum_k A[r][k] * W[k][c]  (+ 12*mask(r)*bias[c] on k-chunk 0)
// (unchanged from round 1 — correctness-proven)
// ---------------------------------------------------------------------------
__global__ __launch_bounds__(256)
void layer_gemm_kernel(const float* __restrict__ A, int lda, int scaleA,
                       const float* __restrict__ W,
                       const float* __restrict__ bias,
                       const int* __restrict__ counts,
                       float* __restrict__ out) {
    __shared__ float Alds[16][128];
    const int ct = blockIdx.x, rt = blockIdx.y, ksb = blockIdx.z;
    const int t = threadIdx.x;
    const int cc = ct * 64 + (t & 63);
    const int wv = t >> 6;
    const int k0 = ksb * 128;

    for (int idx = t; idx < 16 * 32; idx += 256) {
        const int rr = idx >> 5;
        const int kk = (idx & 31) * 4;
        const int row = rt * 16 + rr;
        float4 v = *(const float4*)&A[(size_t)row * lda + k0 + kk];
        if (scaleA) {
            const float inv = 1.f / (float)max(counts[row], 1);
            v.x *= inv; v.y *= inv; v.z *= inv; v.w *= inv;
        }
        *(float4*)&Alds[rr][kk] = v;
    }
    __syncthreads();

    const int r0 = rt * 16 + wv * 4;
    float a0 = 0.f, a1 = 0.f, a2 = 0.f, a3 = 0.f;
#pragma unroll 8
    for (int k = 0; k < 128; ++k) {
        const float wval = W[(size_t)(k0 + k) * HID + cc];
        a0 += Alds[wv * 4 + 0][k] * wval;
        a1 += Alds[wv * 4 + 1][k] * wval;
        a2 += Alds[wv * 4 + 2][k] * wval;
        a3 += Alds[wv * 4 + 3][k] * wval;
    }
    if (ksb == 0) {
        const float bc = bias[cc];
        a0 += (counts[r0 + 0] > 0 ? 12.f : 0.f) * bc;
        a1 += (counts[r0 + 1] > 0 ? 12.f : 0.f) * bc;
        a2 += (counts[r0 + 2] > 0 ? 12.f : 0.f) * bc;
        a3 += (counts[r0 + 3] > 0 ? 12.f : 0.f) * bc;
    }
    atomicAdd(&out[(size_t)(r0 + 0) * 1536 + cc], a0);
    atomicAdd(&out[(size_t)(r0 + 1) * 1536 + cc], a1);
    atomicAdd(&out[(size_t)(r0 + 2) * 1536 + cc], a2);
    atomicAdd(&out[(size_t)(r0 + 3) * 1536 + cc], a3);
}

extern "C" void kernel_launch(void* const* d_in, const int* in_sizes, int n_in,
                              void* d_out, int out_size, void* d_ws, size_t ws_size,
                              hipStream_t stream) {
    const float* x     = (const float*)d_in[0];
    const int*   w2    = (const int*)d_in[1];
    const int*   w3    = (const int*)d_in[2];
    const int*   w4    = (const int*)d_in[3];
    const int*   batch = (const int*)d_in[4];
    const float* W0    = (const float*)d_in[5];
    const float* b0    = (const float*)d_in[6];
    const float* W1    = (const float*)d_in[7];
    const float* b1    = (const float*)d_in[8];
    const float* W2    = (const float*)d_in[9];
    const float* b2    = (const float*)d_in[10];
    float* out = (float*)d_out;

    unsigned char* ws = (unsigned char*)d_ws;
    unsigned int* C32 = (unsigned int*)ws;
    float* Psum = (float*)(ws + PSUM_OFF);
    int* counts = (int*)(ws + COUNTS_OFF);
    float* part = (float*)(ws + PART_OFF);
    const bool use_part = ws_size >= PART_OFF + PART_BYTES;

    hipMemsetAsync(d_ws, 0, ZERO_BYTES, stream);               // C8 + Psum + counts
    hipMemsetAsync(d_out, 0, (size_t)out_size * 4, stream);

    build_c_kernel<<<(N_NODES + 255) / 256, 256, 0, stream>>>(w2, w3, w4, batch, C32, counts);

    if (use_part) {
        pool_gemm_kernel<0><<<dim3(4, KSPLIT), 512, 0, stream>>>(x, ws, part);
        reduce_part_kernel<<<256, 256, 0, stream>>>(part, Psum);
    } else {
        pool_gemm_kernel<1><<<dim3(4, KSPLIT), 512, 0, stream>>>(x, ws, Psum);
    }

    layer_gemm_kernel<<<dim3(8, 8, 4), 256, 0, stream>>>(Psum, HID, 1, W0, b0, counts, out);
    layer_gemm_kernel<<<dim3(8, 8, 4), 256, 0, stream>>>(out, 1536, 0, W1, b1, counts, out + 512);
    layer_gemm_kernel<<<dim3(8, 8, 4), 256, 0, stream>>>(out + 512, 1536, 0, W2, b2, counts, out + 1024);
}